// Round 9
// baseline (476.866 us; speedup 1.0000x reference)
//
#include <hip/hip_runtime.h>
#include <hip/hip_fp16.h>
#include <math.h>

#define NN 100000
#define EE 1600000
#define ET (EE + NN)   // 1,700,000 edges incl self-loops
#define FIN 128
#define D1 64          // H1*C1
#define H1 8
#define C1 8
#define C2 40
#define NEG 0.2f
#define EPSV 1e-16f

#define NBKT 196       // buckets of 512 dst: (99999>>9)+1
#define CHUNK 8192     // edges per scatter block
#define NBB ((ET + CHUNK - 1) / CHUNK)

__device__ __forceinline__ void edge_sd(int e, const int* __restrict__ ei, int& s, int& d) {
  if (e < EE) { s = ei[e]; d = ei[EE + e]; }
  else        { s = e - EE; d = s; }
}

__device__ __forceinline__ float readlane_f(float v, int l) {
  return __int_as_float(__builtin_amdgcn_readlane(__float_as_int(v), l));
}

// ---------- CSR build: bucket histogram ----------
__global__ __launch_bounds__(256) void hist_kernel(const int* __restrict__ ei,
                                                   int* __restrict__ ghist) {
  __shared__ int lh[NBKT];
  int t = threadIdx.x;
  if (t < NBKT) lh[t] = 0;
  __syncthreads();
  for (int e = blockIdx.x * 256 + t; e < ET; e += gridDim.x * 256) {
    int d = (e < EE) ? ei[EE + e] : e - EE;
    atomicAdd(&lh[d >> 9], 1);
  }
  __syncthreads();
  if (t < NBKT && lh[t]) atomicAdd(&ghist[t], lh[t]);
}

__global__ __launch_bounds__(256) void bscan_kernel(const int* __restrict__ ghist,
                                                    int* __restrict__ bbase) {
  __shared__ int sd[256];
  int t = threadIdx.x;
  int v = (t < NBKT) ? ghist[t] : 0;
  sd[t] = v;
  __syncthreads();
  for (int off = 1; off < 256; off <<= 1) {
    int x = sd[t];
    int y = (t >= off) ? sd[t - off] : 0;
    __syncthreads();
    sd[t] = x + y;
    __syncthreads();
  }
  int excl = sd[t] - v;
  if (t < NBKT) bbase[t] = excl;
  if (t == NBKT - 1) bbase[NBKT] = excl + v;
}

// ---------- scatter edges into bucket array (run-reserved, write-local) ----------
__global__ __launch_bounds__(256) void scatter_kernel(const int* __restrict__ ei,
                                                      const int* __restrict__ bbase,
                                                      int* __restrict__ gcur,
                                                      int* __restrict__ barr) {
  __shared__ int lh[NBKT], lres[NBKT], lcur[NBKT];
  int t = threadIdx.x;
  if (t < NBKT) { lh[t] = 0; lcur[t] = 0; }
  __syncthreads();
  int e0 = blockIdx.x * CHUNK;
  int e1 = min(e0 + CHUNK, ET);
  for (int e = e0 + t; e < e1; e += 256) {
    int d = (e < EE) ? ei[EE + e] : e - EE;
    atomicAdd(&lh[d >> 9], 1);
  }
  __syncthreads();
  if (t < NBKT && lh[t]) lres[t] = atomicAdd(&gcur[t], lh[t]);
  __syncthreads();
  for (int e = e0 + t; e < e1; e += 256) {
    int s, d; edge_sd(e, ei, s, d);
    int b = d >> 9;
    int lp = atomicAdd(&lcur[b], 1);
    barr[bbase[b] + lres[b] + lp] = s | ((d & 511) << 17);
  }
}

// ---------- per-bucket: local hist+scan -> rowptr + csr (L2-local writes) ----------
__global__ __launch_bounds__(256) void bucket2csr_kernel(const int* __restrict__ barr,
                                                         const int* __restrict__ bbase,
                                                         int* __restrict__ rowptr,
                                                         int* __restrict__ csr) {
  __shared__ int hist[512];
  __shared__ int sd[256];
  int b = blockIdx.x, t = threadIdx.x;
  int base = bbase[b];
  int cnt = bbase[b + 1] - base;
  hist[t] = 0; hist[t + 256] = 0;
  __syncthreads();
  for (int i = t; i < cnt; i += 256) atomicAdd(&hist[barr[base + i] >> 17], 1);
  __syncthreads();
  int h0 = hist[2 * t], h1 = hist[2 * t + 1], s = h0 + h1;
  sd[t] = s;
  __syncthreads();
  for (int off = 1; off < 256; off <<= 1) {
    int x = sd[t];
    int y = (t >= off) ? sd[t - off] : 0;
    __syncthreads();
    sd[t] = x + y;
    __syncthreads();
  }
  int run = sd[t] - s;   // exclusive base for local dst 2t
  int g = b * 512 + 2 * t;
  if (g < NN) rowptr[g] = base + run;
  if (g + 1 < NN) rowptr[g + 1] = base + run + h0;
  hist[2 * t] = run;
  hist[2 * t + 1] = run + h0;
  __syncthreads();
  for (int i = t; i < cnt; i += 256) {
    int p = barr[base + i];
    int dl = p >> 17;
    int pos = atomicAdd(&hist[dl], 1);
    csr[base + pos] = p & 0x1FFFF;
  }
}

// ---------- layer 1: tiled GEMM 64 nodes x 64 cols, K=128, + att dots ----------
__global__ __launch_bounds__(256) void gemm1_kernel(
    const float* __restrict__ x, const float* __restrict__ W,
    const float* __restrict__ att_s, const float* __restrict__ att_d,
    __half* __restrict__ h, float* __restrict__ as, float* __restrict__ ad) {
  __shared__ float sW[FIN * D1];   // [k][col], 32 KB
  __shared__ float sx[64 * FIN];   // swizzled, 32 KB
  int t = threadIdx.x;
  int node0 = blockIdx.x * 64;
  {
    const float4* Wg = (const float4*)W;
    float4* sWq = (float4*)sW;
    for (int i = t; i < FIN * D1 / 4; i += 256) sWq[i] = Wg[i];
  }
  for (int idx = t; idx < 64 * 32; idx += 256) {
    int node = idx >> 5, kq = idx & 31;
    float4 v = make_float4(0.f, 0.f, 0.f, 0.f);
    if (node0 + node < NN) v = ((const float4*)x)[(size_t)(node0 + node) * 32 + kq];
    *(float4*)&sx[node * FIN + ((kq * 4 + 4 * (node >> 2)) & 127)] = v;
  }
  __syncthreads();
  int lane = t & 63, wid = t >> 6;
  int ng = lane & 15, cgl = lane >> 4;
  int col0 = wid * 16 + cgl * 4;
  float acc[4][4];
#pragma unroll
  for (int a = 0; a < 4; ++a)
#pragma unroll
    for (int c = 0; c < 4; ++c) acc[a][c] = 0.f;
  for (int kk = 0; kk < FIN; kk += 4) {
    float4 xv[4], wv[4];
#pragma unroll
    for (int a = 0; a < 4; ++a) {
      int node = ng * 4 + a;
      xv[a] = *(const float4*)&sx[node * FIN + ((kk + 4 * (node >> 2)) & 127)];
    }
#pragma unroll
    for (int b = 0; b < 4; ++b) wv[b] = *(const float4*)&sW[(kk + b) * D1 + col0];
#pragma unroll
    for (int a = 0; a < 4; ++a) {
      acc[a][0] = fmaf(xv[a].x, wv[0].x, acc[a][0]);
      acc[a][1] = fmaf(xv[a].x, wv[0].y, acc[a][1]);
      acc[a][2] = fmaf(xv[a].x, wv[0].z, acc[a][2]);
      acc[a][3] = fmaf(xv[a].x, wv[0].w, acc[a][3]);
      acc[a][0] = fmaf(xv[a].y, wv[1].x, acc[a][0]);
      acc[a][1] = fmaf(xv[a].y, wv[1].y, acc[a][1]);
      acc[a][2] = fmaf(xv[a].y, wv[1].z, acc[a][2]);
      acc[a][3] = fmaf(xv[a].y, wv[1].w, acc[a][3]);
      acc[a][0] = fmaf(xv[a].z, wv[2].x, acc[a][0]);
      acc[a][1] = fmaf(xv[a].z, wv[2].y, acc[a][1]);
      acc[a][2] = fmaf(xv[a].z, wv[2].z, acc[a][2]);
      acc[a][3] = fmaf(xv[a].z, wv[2].w, acc[a][3]);
      acc[a][0] = fmaf(xv[a].w, wv[3].x, acc[a][0]);
      acc[a][1] = fmaf(xv[a].w, wv[3].y, acc[a][1]);
      acc[a][2] = fmaf(xv[a].w, wv[3].z, acc[a][2]);
      acc[a][3] = fmaf(xv[a].w, wv[3].w, acc[a][3]);
    }
  }
#pragma unroll
  for (int a = 0; a < 4; ++a) {
    int node = node0 + ng * 4 + a;
    if (node < NN) {
      __half2 p01 = __floats2half2_rn(acc[a][0], acc[a][1]);
      __half2 p23 = __floats2half2_rn(acc[a][2], acc[a][3]);
      __half2* hp = (__half2*)&h[(size_t)node * D1 + col0];
      hp[0] = p01; hp[1] = p23;
    }
  }
  float aw_s[4], aw_d[4];
#pragma unroll
  for (int j = 0; j < 4; ++j) { aw_s[j] = att_s[col0 + j]; aw_d[j] = att_d[col0 + j]; }
#pragma unroll
  for (int a = 0; a < 4; ++a) {
    float ps = acc[a][0]*aw_s[0] + acc[a][1]*aw_s[1] + acc[a][2]*aw_s[2] + acc[a][3]*aw_s[3];
    float pd = acc[a][0]*aw_d[0] + acc[a][1]*aw_d[1] + acc[a][2]*aw_d[2] + acc[a][3]*aw_d[3];
    ps += __shfl_xor(ps, 16, 64);
    pd += __shfl_xor(pd, 16, 64);
    int node = node0 + ng * 4 + a;
    if ((cgl & 1) == 0 && node < NN) {
      int head = 2 * wid + (cgl >> 1);
      as[node * H1 + head] = ps;
      ad[node * H1 + head] = pd;
    }
  }
}

// ---------- fused aggregation, layer 1: exp once per (edge,head) via LDS ----------
// exp phase: lane = el*8+hh computes ev for edge el, head hh (8 edges/subgroup),
// stores to wave-private LDS slot. gather: lane (col) reads ev[r*8 + myh]
// (broadcast, conflict-free); den accumulates from the same read.
__global__ __launch_bounds__(256) void agg1_kernel(
    const int* __restrict__ rowptr, const int* __restrict__ csr,
    const float* __restrict__ as, const float* __restrict__ ad,
    const __half* __restrict__ h, const float* __restrict__ b1,
    float* __restrict__ emb) {
  __shared__ float sEv[256];
  int node = blockIdx.x * 4 + (threadIdx.x >> 6);
  if (node >= NN) return;
  int lane = threadIdx.x & 63;
  int wslot = (threadIdx.x >> 6) * 64;
  int myh = lane >> 3;   // head owned in gather phase (col = lane)
  int hh = lane & 7;     // head in exp phase
  int el = lane >> 3;    // edge-within-subgroup in exp phase
  int beg = rowptr[node];
  int end = (node == NN - 1) ? ET : rowptr[node + 1];
  float advh = ad[node * H1 + hh];
  float den0 = 0.f, den1 = 0.f, acc0 = 0.f, acc1 = 0.f;
  for (int i = beg; i < end; i += 64) {
    int nch = min(64, end - i);
    int s64 = csr[i + min(lane, nch - 1)];
    for (int j = 0; j < nch; j += 8) {
      // exp phase: edges j..j+7 (clamped dups for invalid; never read)
      int se = __shfl(s64, j + el, 64);
      float v = as[se * H1 + hh] + advh;
      v = fmaxf(v, NEG * v);
      sEv[wslot + lane] = __expf(v);
      // gather phase: 8 edges, SGPR src ids, LDS-broadcast multipliers
#pragma unroll
      for (int r = 0; r < 8; ++r) {
        if (j + r < nch) {
          int sj = __builtin_amdgcn_readlane(s64, j + r);
          float ev = sEv[wslot + r * 8 + myh];
          float hv = __half2float(h[(size_t)sj * D1 + lane]);
          if (r & 1) { den1 += ev; acc1 = fmaf(hv, ev, acc1); }
          else       { den0 += ev; acc0 = fmaf(hv, ev, acc0); }
        }
      }
    }
  }
  float o = (acc0 + acc1) / (den0 + den1 + EPSV) + b1[lane];
  emb[(size_t)node * D1 + lane] = o > 0.f ? o : expm1f(o);
}

// ---------- layer 2: tiled GEMM 64 nodes x 64 cols (40 real), K=64, + att dots ----------
__global__ __launch_bounds__(256) void gemm2_kernel(
    const float* __restrict__ emb, const float* __restrict__ W2,
    const float* __restrict__ att_s, const float* __restrict__ att_d,
    __half* __restrict__ h2, float* __restrict__ as, float* __restrict__ ad) {
  __shared__ float sW[D1 * D1];    // [k][col64], cols>=40 zero, 16 KB
  __shared__ float se[64 * D1];    // swizzled, 16 KB
  __shared__ float sred_s[64], sred_d[64];
  int t = threadIdx.x;
  int node0 = blockIdx.x * 64;
  for (int i = t; i < D1 * D1; i += 256) {
    int k = i >> 6, c = i & 63;
    sW[i] = (c < C2) ? W2[k * C2 + c] : 0.f;
  }
  for (int idx = t; idx < 64 * 16; idx += 256) {
    int node = idx >> 4, kq = idx & 15;
    float4 v = make_float4(0.f, 0.f, 0.f, 0.f);
    if (node0 + node < NN) v = ((const float4*)emb)[(size_t)(node0 + node) * 16 + kq];
    *(float4*)&se[node * D1 + ((kq * 4 + 4 * (node >> 2)) & 63)] = v;
  }
  if (t < 64) { sred_s[t] = 0.f; sred_d[t] = 0.f; }
  __syncthreads();
  int lane = t & 63, wid = t >> 6;
  int ng = lane & 15, cgl = lane >> 4;
  int col0 = wid * 16 + cgl * 4;
  float acc[4][4];
#pragma unroll
  for (int a = 0; a < 4; ++a)
#pragma unroll
    for (int c = 0; c < 4; ++c) acc[a][c] = 0.f;
  for (int kk = 0; kk < D1; kk += 4) {
    float4 xv[4], wv[4];
#pragma unroll
    for (int a = 0; a < 4; ++a) {
      int node = ng * 4 + a;
      xv[a] = *(const float4*)&se[node * D1 + ((kk + 4 * (node >> 2)) & 63)];
    }
#pragma unroll
    for (int b = 0; b < 4; ++b) wv[b] = *(const float4*)&sW[(kk + b) * D1 + col0];
#pragma unroll
    for (int a = 0; a < 4; ++a) {
      acc[a][0] = fmaf(xv[a].x, wv[0].x, acc[a][0]);
      acc[a][1] = fmaf(xv[a].x, wv[0].y, acc[a][1]);
      acc[a][2] = fmaf(xv[a].x, wv[0].z, acc[a][2]);
      acc[a][3] = fmaf(xv[a].x, wv[0].w, acc[a][3]);
      acc[a][0] = fmaf(xv[a].y, wv[1].x, acc[a][0]);
      acc[a][1] = fmaf(xv[a].y, wv[1].y, acc[a][1]);
      acc[a][2] = fmaf(xv[a].y, wv[1].z, acc[a][2]);
      acc[a][3] = fmaf(xv[a].y, wv[1].w, acc[a][3]);
      acc[a][0] = fmaf(xv[a].z, wv[2].x, acc[a][0]);
      acc[a][1] = fmaf(xv[a].z, wv[2].y, acc[a][1]);
      acc[a][2] = fmaf(xv[a].z, wv[2].z, acc[a][2]);
      acc[a][3] = fmaf(xv[a].z, wv[2].w, acc[a][3]);
      acc[a][0] = fmaf(xv[a].w, wv[3].x, acc[a][0]);
      acc[a][1] = fmaf(xv[a].w, wv[3].y, acc[a][1]);
      acc[a][2] = fmaf(xv[a].w, wv[3].z, acc[a][2]);
      acc[a][3] = fmaf(xv[a].w, wv[3].w, acc[a][3]);
    }
  }
  if (col0 < C2) {
#pragma unroll
    for (int a = 0; a < 4; ++a) {
      int node = node0 + ng * 4 + a;
      if (node < NN) {
        __half2 p01 = __floats2half2_rn(acc[a][0], acc[a][1]);
        __half2 p23 = __floats2half2_rn(acc[a][2], acc[a][3]);
        __half2* hp = (__half2*)&h2[(size_t)node * C2 + col0];
        hp[0] = p01; hp[1] = p23;
      }
    }
    float aw_s[4], aw_d[4];
#pragma unroll
    for (int j = 0; j < 4; ++j) { aw_s[j] = att_s[col0 + j]; aw_d[j] = att_d[col0 + j]; }
#pragma unroll
    for (int a = 0; a < 4; ++a) {
      float ps = acc[a][0]*aw_s[0] + acc[a][1]*aw_s[1] + acc[a][2]*aw_s[2] + acc[a][3]*aw_s[3];
      float pd = acc[a][0]*aw_d[0] + acc[a][1]*aw_d[1] + acc[a][2]*aw_d[2] + acc[a][3]*aw_d[3];
      atomicAdd(&sred_s[ng * 4 + a], ps);
      atomicAdd(&sred_d[ng * 4 + a], pd);
    }
  }
  __syncthreads();
  if (t < 64 && node0 + t < NN) { as[node0 + t] = sred_s[t]; ad[node0 + t] = sred_d[t]; }
}

// ---------- fused aggregation, layer 2: exp once per edge, SGPR multiplier ----------
__global__ __launch_bounds__(256) void agg2_kernel(
    const int* __restrict__ rowptr, const int* __restrict__ csr,
    const float* __restrict__ as, const float* __restrict__ ad,
    const __half* __restrict__ h2, const float* __restrict__ b2,
    float* __restrict__ out) {
  int node = blockIdx.x * 4 + (threadIdx.x >> 6);
  if (node >= NN) return;
  int lane = threadIdx.x & 63;
  int cl = min(lane, C2 - 1);    // lanes 40..63 duplicate col 39 (discarded)
  int beg = rowptr[node];
  int end = (node == NN - 1) ? ET : rowptr[node + 1];
  float adv = ad[node];
  float denp = 0.f, acc0 = 0.f, acc1 = 0.f;
  for (int i = beg; i < end; i += 64) {
    int nch = min(64, end - i);
    int s64 = csr[i + min(lane, nch - 1)];
    // exp phase: one edge per lane
    float v = as[s64] + adv;
    v = fmaxf(v, NEG * v);
    float e = (lane < nch) ? __expf(v) : 0.f;
    denp += e;
    // gather: SGPR src id + SGPR multiplier per edge
    for (int j = 0; j < nch; j += 8) {
#pragma unroll
      for (int r = 0; r < 8; ++r) {
        if (j + r < nch) {
          int sj = __builtin_amdgcn_readlane(s64, j + r);
          float ej = readlane_f(e, j + r);
          float hv = __half2float(h2[(size_t)sj * C2 + cl]);
          if (r & 1) acc1 = fmaf(hv, ej, acc1);
          else       acc0 = fmaf(hv, ej, acc0);
        }
      }
    }
  }
  float den = denp;
#pragma unroll
  for (int off = 1; off < 64; off <<= 1) den += __shfl_xor(den, off, 64);
  float val = (lane < C2) ? (acc0 + acc1) / (den + EPSV) + b2[lane] : -INFINITY;
  float m2 = val;
#pragma unroll
  for (int off = 1; off < 64; off <<= 1) m2 = fmaxf(m2, __shfl_xor(m2, off, 64));
  float ex = (lane < C2) ? __expf(val - m2) : 0.f;
  float sum = ex;
#pragma unroll
  for (int off = 1; off < 64; off <<= 1) sum += __shfl_xor(sum, off, 64);
  if (lane < C2) out[(size_t)node * C2 + lane] = val - m2 - logf(sum);
}

// ---------- launch ----------
extern "C" void kernel_launch(void* const* d_in, const int* in_sizes, int n_in,
                              void* d_out, int out_size, void* d_ws, size_t ws_size,
                              hipStream_t stream) {
  const float* x    = (const float*)d_in[0];
  const float* W1   = (const float*)d_in[1];
  const float* as1w = (const float*)d_in[2];
  const float* ad1w = (const float*)d_in[3];
  const float* b1   = (const float*)d_in[4];
  const float* W2   = (const float*)d_in[5];
  const float* as2w = (const float*)d_in[6];
  const float* ad2w = (const float*)d_in[7];
  const float* b2   = (const float*)d_in[8];
  const int*   ei   = (const int*)d_in[9];

  float* out   = (float*)d_out;
  float* outls = out;                    // [N,40] log_softmax
  float* emb   = out + (long)NN * C2;    // [N,64] emb

  char* wsb = (char*)d_ws;
  __half* h1   = (__half*)wsb; wsb += sizeof(__half) * (size_t)NN * D1;
  __half* h2   = (__half*)wsb; wsb += sizeof(__half) * ((size_t)NN * C2 + 64);  // +64 pad
  float* asrc1 = (float*)wsb; wsb += sizeof(float) * (size_t)NN * H1;
  float* adst1 = (float*)wsb; wsb += sizeof(float) * (size_t)NN * H1;
  float* asrc2 = (float*)wsb; wsb += sizeof(float) * (size_t)NN;
  float* adst2 = (float*)wsb; wsb += sizeof(float) * (size_t)NN;
  int* rowptr  = (int*)wsb;   wsb += sizeof(int) * (size_t)NN;
  int* ghist   = (int*)wsb;   wsb += sizeof(int) * (NBKT + 4);
  int* gcur    = (int*)wsb;   wsb += sizeof(int) * (NBKT + 4);
  int* bbase   = (int*)wsb;   wsb += sizeof(int) * (NBKT + 4);
  int* barr    = (int*)wsb;   wsb += sizeof(int) * (size_t)ET;
  int* csr     = (int*)wsb;   wsb += sizeof(int) * (size_t)ET;

  // CSR build (bucketed; per call since ws is re-poisoned)
  hipMemsetAsync(ghist, 0, sizeof(int) * 2 * (NBKT + 4), stream);  // ghist + gcur
  hist_kernel<<<256, 256, 0, stream>>>(ei, ghist);
  bscan_kernel<<<1, 256, 0, stream>>>(ghist, bbase);
  scatter_kernel<<<NBB, 256, 0, stream>>>(ei, bbase, gcur, barr);
  bucket2csr_kernel<<<NBKT, 256, 0, stream>>>(barr, bbase, rowptr, csr);

  // layer 1
  gemm1_kernel<<<(NN + 63) / 64, 256, 0, stream>>>(x, W1, as1w, ad1w, h1, asrc1, adst1);
  agg1_kernel<<<(NN + 3) / 4, 256, 0, stream>>>(rowptr, csr, asrc1, adst1, h1, b1, emb);

  // layer 2 (gemm + attdot fused)
  gemm2_kernel<<<(NN + 63) / 64, 256, 0, stream>>>(emb, W2, as2w, ad2w, h2, asrc2, adst2);
  agg2_kernel<<<(NN + 3) / 4, 256, 0, stream>>>(rowptr, csr, asrc2, adst2, h2, b2, outls);
}